// Round 5
// baseline (150.411 us; speedup 1.0000x reference)
//
#include <hip/hip_runtime.h>

#define B_ 512
#define L_ 8192
#define N_ 128
#define S_ 256
#define DELIM_ 5
#define T_ 1024          // table kernel: 16 waves/block, one block per row
#define NW_ (T_ / 64)
#define TW_ 256          // writer: fill-shaped lean blocks
#define GW_ 2048         // writer grid: 8 blocks/CU, 8 sentences per wave

typedef float __attribute__((ext_vector_type(4))) f32x4;

// ---------------------------------------------------------------------------
// Kernel A: per-row delimiter scan -> chunk table {start, cl, len} (+ len_doc).
// ALL data-dependent work (ballots, len_sent, len_doc) happens here, while the
// row is L2-hot from phase 1's read by THIS block. tbl[s] = {start,cl,len,0}.
// ---------------------------------------------------------------------------
__global__ __launch_bounds__(T_) void table_kernel(const int* __restrict__ x,
                                                   int4* __restrict__ tbl,
                                                   float* __restrict__ len_doc) {
    const int b = blockIdx.x;
    const int t = threadIdx.x;
    const int lane = t & 63;
    const int w = t >> 6;
    const int* __restrict__ row = x + (size_t)b * L_;

    __shared__ int s_wsum[NW_];
    __shared__ int s_dpos[N_ - 1];  // first 127 delimiter positions (tail merge)
    __shared__ int s_start[N_];
    __shared__ int s_cl[N_];
    __shared__ int s_doc[NW_];

    // ---- phase 1a: coalesced int4 loads; count delims ----
    const int4 r0 = ((const int4*)row)[t];        // tokens [4t, 4t+4)
    const int4 r1 = ((const int4*)row)[t + T_];   // tokens [4096+4t, ...)

    const int c0 = (r0.x == DELIM_) + (r0.y == DELIM_) + (r0.z == DELIM_) + (r0.w == DELIM_);
    const int c1 = (r1.x == DELIM_) + (r1.y == DELIM_) + (r1.z == DELIM_) + (r1.w == DELIM_);
    const int packed = c0 | (c1 << 16);

    // wave inclusive scan of packed counts
    int sv = packed;
#pragma unroll
    for (int d = 1; d < 64; d <<= 1) {
        int n = __shfl_up(sv, d, 64);
        if (lane >= d) sv += n;
    }
    if (lane == 63) s_wsum[w] = sv;
    __syncthreads();

    int woff = 0, tot = 0;
#pragma unroll
    for (int i = 0; i < NW_; ++i) {
        const int s = s_wsum[i];
        if (i < w) woff += s;
        tot += s;
    }
    const int pre = woff + sv - packed;         // exclusive prefix (packed)
    const int c0tot = tot & 0xffff;             // total delims in first half
    const int m = c0tot + (tot >> 16);          // total delims in row
    const int off0 = pre & 0xffff;
    const int off1 = c0tot + (pre >> 16);

    // ---- phase 1b: emit ordered delimiter positions from registers ----
    if (c0 > 0 && off0 < N_ - 1) {
        int o = off0;
        const int p = 4 * t;
        if (r0.x == DELIM_) { if (o < N_ - 1) s_dpos[o] = p;     ++o; }
        if (r0.y == DELIM_) { if (o < N_ - 1) s_dpos[o] = p + 1; ++o; }
        if (r0.z == DELIM_) { if (o < N_ - 1) s_dpos[o] = p + 2; ++o; }
        if (r0.w == DELIM_) { if (o < N_ - 1) s_dpos[o] = p + 3; ++o; }
    }
    if (c1 > 0 && off1 < N_ - 1) {
        int o = off1;
        const int p = 4 * T_ + 4 * t;
        if (r1.x == DELIM_) { if (o < N_ - 1) s_dpos[o] = p;     ++o; }
        if (r1.y == DELIM_) { if (o < N_ - 1) s_dpos[o] = p + 1; ++o; }
        if (r1.z == DELIM_) { if (o < N_ - 1) s_dpos[o] = p + 2; ++o; }
        if (r1.w == DELIM_) { if (o < N_ - 1) s_dpos[o] = p + 3; ++o; }
    }
    __syncthreads();

    // ---- chunk table (LDS) ----
    if (t < N_) {
        const int k = t;
        const int mc = (m < N_ - 1) ? m : (N_ - 1);  // last used chunk index
        int start = 0, cl = 0;
        if (k <= mc) {
            start = (k == 0) ? 0 : (s_dpos[k - 1] + 1);
            const int end = (k < mc) ? s_dpos[k] : L_;  // virtual rpad[L] = DELIM
            const int size = end - start + 1;           // delim belongs to chunk
            cl = (size <= 1) ? 0 : (size < S_ ? size : S_);  // lone delim -> PAD
        }
        s_start[k] = start;
        s_cl[k] = cl;
    }
    __syncthreads();

    // ---- len pass: wave w -> sentences k = i*NW_+w; row is L2-hot ----
    int doccnt = 0;
#pragma unroll
    for (int i = 0; i < (N_ / NW_); ++i) {
        const int k = i * NW_ + w;
        const int start = s_start[k];   // wave-uniform LDS broadcast
        const int cl = s_cl[k];
        int len = 0;
        if (cl > 0) {                   // wave-uniform
#pragma unroll
            for (int j = 0; j < 4; ++j) {
                const int e = 64 * j + lane;
                const int idx = start + e;
                int v = row[idx < L_ ? idx : L_ - 1];
                v = (idx == L_) ? DELIM_ : v;
                v = (e < cl) ? v : 0;
                len += __popcll(__ballot(v != 0));
            }
        }
        doccnt += (len > 0);
        if (lane == 0) tbl[b * N_ + k] = make_int4(start, cl, len, 0);
    }

    if (lane == 0) s_doc[w] = doccnt;
    __syncthreads();
    if (t == 0) {
        int d = 0;
#pragma unroll
        for (int i = 0; i < NW_; ++i) d += s_doc[i];
        len_doc[b] = (float)d;
    }
}

// ---------------------------------------------------------------------------
// Kernel B: pure masked-copy writer at fillBuffer shape. One wave == one
// sentence (64 lanes x float4 == 256 elems). Grid-stride over 65536 sentences.
// mask is computed (no loads) and stored FIRST; otp is 4 dword gathers +
// one dwordx4 store. No LDS, no barriers, no ballots, no atomics.
// ---------------------------------------------------------------------------
__global__ __launch_bounds__(TW_, 8) void write_kernel(const int* __restrict__ x,
                                                       const int4* __restrict__ tbl,
                                                       float* __restrict__ otp,
                                                       float* __restrict__ mask) {
    const int lane = threadIdx.x & 63;
    const int wid = (blockIdx.x * TW_ + threadIdx.x) >> 6;
    const int nw = (GW_ * TW_) >> 6;
    const int e0 = lane << 2;

    for (int s = wid; s < B_ * N_; s += nw) {
        const int4 tc = tbl[s];                 // wave-uniform broadcast
        const int start = tc.x, cl = tc.y, len = tc.z;

        // mask: pure compute, no dependency -> issue first
        f32x4 mk;
        mk.x = (e0 + 0 < len) ? 1.0f : 0.0f;
        mk.y = (e0 + 1 < len) ? 1.0f : 0.0f;
        mk.z = (e0 + 2 < len) ? 1.0f : 0.0f;
        mk.w = (e0 + 3 < len) ? 1.0f : 0.0f;
        *(f32x4*)(mask + (size_t)s * S_ + e0) = mk;   // aligned dwordx4

        f32x4 tf = {0.f, 0.f, 0.f, 0.f};
        if (cl > 0) {                            // wave-uniform skip
            const int b = s >> 7;                // s / N_
            const int* __restrict__ row = x + (size_t)b * L_;
#pragma unroll
            for (int j = 0; j < 4; ++j) {
                const int e = e0 + j;
                const int idx = start + e;
                int v = row[idx < L_ ? idx : L_ - 1];
                v = (idx == L_) ? DELIM_ : v;    // virtual trailing delimiter
                if (e < cl) tf[j] = (float)v;
            }
        }
        *(f32x4*)(otp + (size_t)s * S_ + e0) = tf;    // aligned dwordx4
    }
}

// ---------------------------------------------------------------------------
// Fallback: proven R4 monolithic kernel (workspace too small).
// ---------------------------------------------------------------------------
__global__ __launch_bounds__(T_, 8) void split_kernel(const int* __restrict__ x,
                                                      float* __restrict__ otp,
                                                      float* __restrict__ len_doc,
                                                      float* __restrict__ mask) {
    const int b = blockIdx.x;
    const int t = threadIdx.x;
    const int lane = t & 63;
    const int w = t >> 6;
    const int* __restrict__ row = x + (size_t)b * L_;

    __shared__ int s_wsum[NW_];
    __shared__ int s_dpos[N_ - 1];
    __shared__ int s_doc[NW_];

    const int4 r0 = ((const int4*)row)[t];
    const int4 r1 = ((const int4*)row)[t + T_];

    const int c0 = (r0.x == DELIM_) + (r0.y == DELIM_) + (r0.z == DELIM_) + (r0.w == DELIM_);
    const int c1 = (r1.x == DELIM_) + (r1.y == DELIM_) + (r1.z == DELIM_) + (r1.w == DELIM_);
    const int packed = c0 | (c1 << 16);

    int sv = packed;
#pragma unroll
    for (int d = 1; d < 64; d <<= 1) {
        int n = __shfl_up(sv, d, 64);
        if (lane >= d) sv += n;
    }
    if (lane == 63) s_wsum[w] = sv;
    __syncthreads();

    int woff = 0, tot = 0;
#pragma unroll
    for (int i = 0; i < NW_; ++i) {
        const int s = s_wsum[i];
        if (i < w) woff += s;
        tot += s;
    }
    const int pre = woff + sv - packed;
    const int c0tot = tot & 0xffff;
    const int m = c0tot + (tot >> 16);
    const int off0 = pre & 0xffff;
    const int off1 = c0tot + (pre >> 16);

    if (c0 > 0 && off0 < N_ - 1) {
        int o = off0;
        const int p = 4 * t;
        if (r0.x == DELIM_) { if (o < N_ - 1) s_dpos[o] = p;     ++o; }
        if (r0.y == DELIM_) { if (o < N_ - 1) s_dpos[o] = p + 1; ++o; }
        if (r0.z == DELIM_) { if (o < N_ - 1) s_dpos[o] = p + 2; ++o; }
        if (r0.w == DELIM_) { if (o < N_ - 1) s_dpos[o] = p + 3; ++o; }
    }
    if (c1 > 0 && off1 < N_ - 1) {
        int o = off1;
        const int p = 4 * T_ + 4 * t;
        if (r1.x == DELIM_) { if (o < N_ - 1) s_dpos[o] = p;     ++o; }
        if (r1.y == DELIM_) { if (o < N_ - 1) s_dpos[o] = p + 1; ++o; }
        if (r1.z == DELIM_) { if (o < N_ - 1) s_dpos[o] = p + 2; ++o; }
        if (r1.w == DELIM_) { if (o < N_ - 1) s_dpos[o] = p + 3; ++o; }
    }
    __syncthreads();

    const int mc = (m < N_ - 1) ? m : (N_ - 1);
    float* __restrict__ otp_b = otp + (size_t)b * N_ * S_;
    float* __restrict__ msk_b = mask + (size_t)b * N_ * S_;
    int doccnt = 0;
#pragma unroll
    for (int i = 0; i < (N_ / NW_); ++i) {
        const int k = i * NW_ + w;
        int cl = 0, start = 0;
        if (k <= mc) {
            start = (k == 0) ? 0 : (s_dpos[k - 1] + 1);
            const int end = (k < mc) ? s_dpos[k] : L_;
            const int size = end - start + 1;
            cl = (size <= 1) ? 0 : (size < S_ ? size : S_);
        }
        int t0 = 0, t1 = 0, t2 = 0, t3 = 0;
        int len = 0;
        if (cl > 0) {
            { const int idx = start + lane;       int v = row[idx < L_ ? idx : L_ - 1]; v = (idx == L_) ? DELIM_ : v; t0 = (lane < cl) ? v : 0; }
            { const int idx = start + 64 + lane;  int v = row[idx < L_ ? idx : L_ - 1]; v = (idx == L_) ? DELIM_ : v; t1 = (64 + lane < cl) ? v : 0; }
            { const int idx = start + 128 + lane; int v = row[idx < L_ ? idx : L_ - 1]; v = (idx == L_) ? DELIM_ : v; t2 = (128 + lane < cl) ? v : 0; }
            { const int idx = start + 192 + lane; int v = row[idx < L_ ? idx : L_ - 1]; v = (idx == L_) ? DELIM_ : v; t3 = (192 + lane < cl) ? v : 0; }
            len += __popcll(__ballot(t0 != 0));
            len += __popcll(__ballot(t1 != 0));
            len += __popcll(__ballot(t2 != 0));
            len += __popcll(__ballot(t3 != 0));
        }
        otp_b[(size_t)k * S_ + lane]       = (float)t0;
        otp_b[(size_t)k * S_ + lane + 64]  = (float)t1;
        otp_b[(size_t)k * S_ + lane + 128] = (float)t2;
        otp_b[(size_t)k * S_ + lane + 192] = (float)t3;
        msk_b[(size_t)k * S_ + lane]       = (lane       < len) ? 1.0f : 0.0f;
        msk_b[(size_t)k * S_ + lane + 64]  = (lane + 64  < len) ? 1.0f : 0.0f;
        msk_b[(size_t)k * S_ + lane + 128] = (lane + 128 < len) ? 1.0f : 0.0f;
        msk_b[(size_t)k * S_ + lane + 192] = (lane + 192 < len) ? 1.0f : 0.0f;
        doccnt += (len > 0);
    }

    if (lane == 0) s_doc[w] = doccnt;
    __syncthreads();
    if (t == 0) {
        int d = 0;
#pragma unroll
        for (int i = 0; i < NW_; ++i) d += s_doc[i];
        len_doc[b] = (float)d;
    }
}

extern "C" void kernel_launch(void* const* d_in, const int* in_sizes, int n_in,
                              void* d_out, int out_size, void* d_ws, size_t ws_size,
                              hipStream_t stream) {
    const int* x = (const int*)d_in[0];
    float* out = (float*)d_out;

    // d_out layout (flat, return order): otp[B*N*S] | len_doc[B] | mask[B*N*S]
    float* otp = out;
    float* len_doc = out + (size_t)B_ * N_ * S_;
    float* mask = len_doc + B_;

    const size_t tbl_bytes = (size_t)B_ * N_ * sizeof(int4);   // 1 MiB
    if (d_ws != nullptr && ws_size >= tbl_bytes) {
        int4* tbl = (int4*)d_ws;
        table_kernel<<<B_, T_, 0, stream>>>(x, tbl, len_doc);
        write_kernel<<<GW_, TW_, 0, stream>>>(x, tbl, otp, mask);
    } else {
        split_kernel<<<B_, T_, 0, stream>>>(x, otp, len_doc, mask);
    }
}

// Round 6
// 141.732 us; speedup vs baseline: 1.0612x; 1.0612x over previous
//
#include <hip/hip_runtime.h>

#define B_ 512
#define L_ 8192
#define N_ 128
#define S_ 256
#define DELIM_ 5
#define T_ 1024          // 16 waves/block; 2 blocks/CU (thread-limited), 512 blocks = exactly 1 round
#define NW_ (T_ / 64)

// Best-measured variant (R4, 142.1 us; statistically tied with R0's 141.7).
// Single lean kernel, one block per row, one dispatch total.
// Phase 1: coalesced int4 row read -> registers only; packed block scan ->
//          ordered delimiter positions s_dpos (~512 B of LDS).
// Phase 2: wave w handles sentence k = i*NW_+w; start/cl derived inline from
//          s_dpos + m. Tokens gathered straight from global x (row is
//          same-XCD L2-hot from phase 1). Element layout e = 64*j + lane:
//          every load/store is a coalesced 256 B dword op (wider/nt stores
//          measured neutral in R1/R2). ballot+popc for len_sent; LDS reduce
//          for len_doc. No atomics. LDS total ~640 B.
__global__ __launch_bounds__(T_, 8) void split_kernel(const int* __restrict__ x,
                                                      float* __restrict__ otp,
                                                      float* __restrict__ len_doc,
                                                      float* __restrict__ mask) {
    const int b = blockIdx.x;
    const int t = threadIdx.x;
    const int lane = t & 63;
    const int w = t >> 6;
    const int* __restrict__ row = x + (size_t)b * L_;

    __shared__ int s_wsum[NW_];
    __shared__ int s_dpos[N_ - 1];  // first 127 delimiter positions (tail merge)
    __shared__ int s_doc[NW_];

    // ---- phase 1a: coalesced int4 loads; count delims ----
    const int4 r0 = ((const int4*)row)[t];        // tokens [4t, 4t+4)
    const int4 r1 = ((const int4*)row)[t + T_];   // tokens [4096+4t, ...)

    const int c0 = (r0.x == DELIM_) + (r0.y == DELIM_) + (r0.z == DELIM_) + (r0.w == DELIM_);
    const int c1 = (r1.x == DELIM_) + (r1.y == DELIM_) + (r1.z == DELIM_) + (r1.w == DELIM_);
    const int packed = c0 | (c1 << 16);

    // wave inclusive scan of packed counts
    int sv = packed;
#pragma unroll
    for (int d = 1; d < 64; d <<= 1) {
        int n = __shfl_up(sv, d, 64);
        if (lane >= d) sv += n;
    }
    if (lane == 63) s_wsum[w] = sv;
    __syncthreads();                               // barrier 1

    int woff = 0, tot = 0;
#pragma unroll
    for (int i = 0; i < NW_; ++i) {
        const int s = s_wsum[i];
        if (i < w) woff += s;
        tot += s;
    }
    const int pre = woff + sv - packed;         // exclusive prefix (packed)
    const int c0tot = tot & 0xffff;             // total delims in first half
    const int m = c0tot + (tot >> 16);          // total delims in row
    const int off0 = pre & 0xffff;
    const int off1 = c0tot + (pre >> 16);

    // ---- phase 1b: emit ordered delimiter positions from registers ----
    if (c0 > 0 && off0 < N_ - 1) {
        int o = off0;
        const int p = 4 * t;
        if (r0.x == DELIM_) { if (o < N_ - 1) s_dpos[o] = p;     ++o; }
        if (r0.y == DELIM_) { if (o < N_ - 1) s_dpos[o] = p + 1; ++o; }
        if (r0.z == DELIM_) { if (o < N_ - 1) s_dpos[o] = p + 2; ++o; }
        if (r0.w == DELIM_) { if (o < N_ - 1) s_dpos[o] = p + 3; ++o; }
    }
    if (c1 > 0 && off1 < N_ - 1) {
        int o = off1;
        const int p = 4 * T_ + 4 * t;
        if (r1.x == DELIM_) { if (o < N_ - 1) s_dpos[o] = p;     ++o; }
        if (r1.y == DELIM_) { if (o < N_ - 1) s_dpos[o] = p + 1; ++o; }
        if (r1.z == DELIM_) { if (o < N_ - 1) s_dpos[o] = p + 2; ++o; }
        if (r1.w == DELIM_) { if (o < N_ - 1) s_dpos[o] = p + 3; ++o; }
    }
    __syncthreads();                               // barrier 2

    // ---- phase 2: start/cl inline from s_dpos; gather global; stream out ----
    const int mc = (m < N_ - 1) ? m : (N_ - 1);    // last used chunk index
    float* __restrict__ otp_b = otp + (size_t)b * N_ * S_;
    float* __restrict__ msk_b = mask + (size_t)b * N_ * S_;
    int doccnt = 0;
#pragma unroll
    for (int i = 0; i < (N_ / NW_); ++i) {
        const int k = i * NW_ + w;
        int cl = 0, start = 0;
        if (k <= mc) {                             // wave-uniform
            start = (k == 0) ? 0 : (s_dpos[k - 1] + 1);   // LDS broadcast
            const int end = (k < mc) ? s_dpos[k] : L_;    // virtual rpad[L]=DELIM
            const int size = end - start + 1;             // delim belongs to chunk
            cl = (size <= 1) ? 0 : (size < S_ ? size : S_);  // lone delim -> PAD
        }
        int t0 = 0, t1 = 0, t2 = 0, t3 = 0;
        int len = 0;
        if (cl > 0) {                              // wave-uniform skip
            // branchless clamped gather; virtual trailing delimiter at idx==L_
            {
                const int idx = start + lane;
                int v0 = row[idx < L_ ? idx : L_ - 1];
                v0 = (idx == L_) ? DELIM_ : v0;
                t0 = (lane < cl) ? v0 : 0;
            }
            {
                const int idx = start + 64 + lane;
                int v1 = row[idx < L_ ? idx : L_ - 1];
                v1 = (idx == L_) ? DELIM_ : v1;
                t1 = (64 + lane < cl) ? v1 : 0;
            }
            {
                const int idx = start + 128 + lane;
                int v2 = row[idx < L_ ? idx : L_ - 1];
                v2 = (idx == L_) ? DELIM_ : v2;
                t2 = (128 + lane < cl) ? v2 : 0;
            }
            {
                const int idx = start + 192 + lane;
                int v3 = row[idx < L_ ? idx : L_ - 1];
                v3 = (idx == L_) ? DELIM_ : v3;
                t3 = (192 + lane < cl) ? v3 : 0;
            }
            len += __popcll(__ballot(t0 != 0));    // wave-uniform nonzero count
            len += __popcll(__ballot(t1 != 0));
            len += __popcll(__ballot(t2 != 0));
            len += __popcll(__ballot(t3 != 0));
        }
        // stores unconditional: cl==0 sentences must emit zeros too
        otp_b[(size_t)k * S_ + lane]       = (float)t0;
        otp_b[(size_t)k * S_ + lane + 64]  = (float)t1;
        otp_b[(size_t)k * S_ + lane + 128] = (float)t2;
        otp_b[(size_t)k * S_ + lane + 192] = (float)t3;
        msk_b[(size_t)k * S_ + lane]       = (lane       < len) ? 1.0f : 0.0f;
        msk_b[(size_t)k * S_ + lane + 64]  = (lane + 64  < len) ? 1.0f : 0.0f;
        msk_b[(size_t)k * S_ + lane + 128] = (lane + 128 < len) ? 1.0f : 0.0f;
        msk_b[(size_t)k * S_ + lane + 192] = (lane + 192 < len) ? 1.0f : 0.0f;
        doccnt += (len > 0);
    }

    // ---- len_doc: one LDS reduction per block, no atomics ----
    if (lane == 0) s_doc[w] = doccnt;
    __syncthreads();                               // barrier 3
    if (t == 0) {
        int d = 0;
#pragma unroll
        for (int i = 0; i < NW_; ++i) d += s_doc[i];
        len_doc[b] = (float)d;
    }
}

extern "C" void kernel_launch(void* const* d_in, const int* in_sizes, int n_in,
                              void* d_out, int out_size, void* d_ws, size_t ws_size,
                              hipStream_t stream) {
    const int* x = (const int*)d_in[0];
    float* out = (float*)d_out;

    // d_out layout (flat, return order): otp[B*N*S] | len_doc[B] | mask[B*N*S]
    float* otp = out;
    float* len_doc = out + (size_t)B_ * N_ * S_;
    float* mask = len_doc + B_;

    split_kernel<<<B_, T_, 0, stream>>>(x, otp, len_doc, mask);
}